// Round 11
// baseline (10359.625 us; speedup 1.0000x reference)
//
#include <hip/hip_runtime.h>

#define NFULL 33024
#define FPS_T 512
#define BST   99072    // per-batch stride in XYZ SoA: 3*33024
#define NB    4        // FPS blocks per batch
#define PPB   8256     // points per FPS block (4*8256 = 33024)

// ---- x1[b,o,k] = sum_i f[b,i] * ps_w[i,o,k] + ps_b[o] ; col = o*256+k ----
__global__ void k_ps(const float* __restrict__ feat,
                     const float* __restrict__ psw,
                     const float* __restrict__ psb,
                     float* __restrict__ out)
{
    __shared__ float fs[16384];   // all of f (32x512), 64 KB
    const int tid = threadIdx.x;
    for (int k = tid; k < 16384; k += 256) fs[k] = feat[k];
    __syncthreads();
    const int col = blockIdx.x * 256 + tid;    // 0..32767
    float acc[32];
    #pragma unroll
    for (int b = 0; b < 32; ++b) acc[b] = 0.f;
    for (int i = 0; i < 512; i += 4) {
        const float w0 = psw[(i+0)*32768 + col];
        const float w1 = psw[(i+1)*32768 + col];
        const float w2 = psw[(i+2)*32768 + col];
        const float w3 = psw[(i+3)*32768 + col];
        #pragma unroll
        for (int b = 0; b < 32; ++b) {
            const float4 f4 = *(const float4*)&fs[b*512 + i];
            acc[b] += f4.x*w0 + f4.y*w1 + f4.z*w2 + f4.w*w3;
        }
    }
    const float bias = psb[col >> 8];
    #pragma unroll
    for (int b = 0; b < 32; ++b) out[b*32768 + col] = acc[b] + bias;
}

// ---- fb[wsel][b,o] = sum_{i<512} f[b,i] * w[o*640 + 128 + i]  (fr-fold) ----
__global__ void k_fb(const float* __restrict__ feat,
                     const float* __restrict__ wa, const float* __restrict__ wb,
                     const float* __restrict__ wc, const float* __restrict__ wd,
                     float* __restrict__ fb)
{
    const int tid = blockIdx.x * 256 + threadIdx.x;  // 0..16383
    const int wsel = tid >> 12;
    const int r = tid & 4095;
    const int b = r >> 7, o = r & 127;
    const float* w = (wsel == 0 ? wa : wsel == 1 ? wb : wsel == 2 ? wc : wd) + o*640 + 128;
    const float* f = feat + b*512;
    float acc = 0.f;
    for (int i = 0; i < 512; i += 4) {
        const float4 wv = *(const float4*)(w + i);
        const float4 fv = *(const float4*)(f + i);
        acc += wv.x*fv.x + wv.y*fv.y + wv.z*fv.z + wv.w*fv.w;
    }
    fb[tid] = acc;
}

// ---- out[b,o,n] = relu?( sum_i w[o,i]*x[b,i,n] + bias[o] + fb[b,o] + add[b,o,n] )
__global__ void k_conv(const float* __restrict__ x,
                       const float* __restrict__ w,
                       const float* __restrict__ bias,
                       const float* __restrict__ fb,
                       const float* __restrict__ add,
                       float* __restrict__ out,
                       const int O, const int K, const int ldw, const int relu)
{
    const int bo = blockIdx.x;
    const int b = bo / O;
    const int o = bo - b * O;
    const int n = threadIdx.x;
    const float* __restrict__ wr = w + o * ldw;
    const float* __restrict__ xb = x + (b * K) * 256 + n;
    float acc = 0.f;
    for (int i = 0; i < K; i += 4) {
        const float4 wv = *(const float4*)(wr + i);
        acc += wv.x * xb[(i+0) << 8];
        acc += wv.y * xb[(i+1) << 8];
        acc += wv.z * xb[(i+2) << 8];
        acc += wv.w * xb[(i+3) << 8];
    }
    acc += bias[o];
    if (fb)   acc += fb[b * O + o];
    if (add)  acc += add[bo * 256 + n];
    if (relu) acc = fmaxf(acc, 0.f);
    out[bo * 256 + n] = acc;
}

// ---- pcd transpose -> d_out ; completion points -> XYZ SoA [0,256) ----
__global__ void k_pcd(const float* __restrict__ comp,
                      float* __restrict__ pcd_out,
                      float* __restrict__ XYZ)
{
    const int tid = blockIdx.x * 256 + threadIdx.x;  // 0..8191
    const int b = tid >> 8, n = tid & 255;
    const float cx = comp[(b*3+0)*256 + n];
    const float cy = comp[(b*3+1)*256 + n];
    const float cz = comp[(b*3+2)*256 + n];
    pcd_out[tid*3+0] = cx; pcd_out[tid*3+1] = cy; pcd_out[tid*3+2] = cz;
    float* Xb = XYZ + b*BST;
    Xb[n]           = cx;
    Xb[33024  + n]  = cy;
    Xb[66048  + n]  = cz;
}

// ---- partial (AoS) -> XYZ SoA [256,33024) per batch (bitwise) ----
__global__ void k_copy(const float* __restrict__ partial, float* __restrict__ XYZ)
{
    const int p = blockIdx.x*256 + threadIdx.x;   // 0..1048575 (32*32768)
    const int b = p >> 15, i = p & 32767;
    const float x = partial[p*3+0];
    const float y = partial[p*3+1];
    const float z = partial[p*3+2];
    float* Xb = XYZ + b*BST;
    Xb[256 + i]          = x;
    Xb[33024 + 256 + i]  = y;
    Xb[66048 + 256 + i]  = z;
}

// ================= farthest point sampling (multi-block) =================
// 4 blocks per batch (128 blocks = 128 CUs; 1 block/CU via 132KB LDS).
// Each block owns 8256 points: x/y/z/d ALL in LDS -> zero global streaming
// in the step loop. Per step each block publishes a 32B candidate record
// (val, global idx, x, y, z) to d_ws with agent-scope release; all blocks
// poll the 4 records (acquire, 0xAA-sentinel) and redundantly compute the
// winner by (max val, tie -> min global idx) == np.argmax first-max across
// the concatenated order. Records are re-sentineled via hipMemsetAsync at
// the top of every kernel_launch -> no cross-call state. Co-residency: 128
// blocks <= 256 CUs, publish never depends on a later block -> no deadlock.
// Distance math bitwise-np-exact (no fma); in-thread scan ascending (jo
// major, c minor); strict > keeps first max.

struct Rec { float val; unsigned int idx; float x, y, z; unsigned int q0, q1, q2; };

#define FBODY(xx, yy, zz, dd, cc) { \
    const float dx = __fsub_rn((xx), lx); \
    const float dy = __fsub_rn((yy), ly); \
    const float dz = __fsub_rn((zz), lz); \
    const float dist = __fadd_rn(__fadd_rn(__fmul_rn(dx,dx), __fmul_rn(dy,dy)), \
                                 __fmul_rn(dz,dz)); \
    dd = fminf(dd, dist); \
    if (dd > bestv) { bestv = dd; bestc = (cc); } }

__launch_bounds__(FPS_T)
__global__ void k_fps(const float* __restrict__ XYZ, Rec* __restrict__ R,
                      float* __restrict__ outp)
{
    __shared__ __align__(16) float xs[PPB], ys[PPB], zs[PPB], ds[PPB]; // 132KB
    __shared__ float redv[2][8];
    __shared__ int   redi[2][8];

    const int bx   = blockIdx.x;
    const int b    = bx >> 2;       // batch
    const int blk  = bx & 3;        // block within batch
    const int boff = blk * PPB;
    const int t    = threadIdx.x;
    const int t4   = t << 2;
    const float* __restrict__ Xb = XYZ + b*BST;
    const float* __restrict__ Yb = Xb + 33024;
    const float* __restrict__ Zb = Xb + 66048;
    Rec* __restrict__ Rb = R + b*512*NB;
    const float NEG = -__builtin_inff();

    // publish the init record (centroid = global point 0)
    if (blk == 0 && t == 0) {
        Rec* rp = Rb;   // slot (s=0, k=0)
        rp->val = 0.f; rp->x = Xb[0]; rp->y = Yb[0]; rp->z = Zb[0];
        __hip_atomic_store(&rp->idx, 0u, __ATOMIC_RELEASE, __HIP_MEMORY_SCOPE_AGENT);
    }

    // stage this block's slice into LDS
    for (int k = t; k < PPB; k += FPS_T) {
        xs[k] = Xb[boff + k];
        ys[k] = Yb[boff + k];
        zs[k] = Zb[boff + k];
        ds[k] = 1.0e10f;
    }
    __syncthreads();

    float lx, ly, lz;
    {   // gather init record (lane 0 polls, broadcast)
        const int lane = t & 63;
        float gx = 0.f, gy = 0.f, gz = 0.f;
        if (lane == 0) {
            Rec* rp = Rb;
            unsigned id;
            do { id = __hip_atomic_load(&rp->idx, __ATOMIC_ACQUIRE, __HIP_MEMORY_SCOPE_AGENT); }
            while (id == 0xAAAAAAAAu);
            gx = rp->x; gy = rp->y; gz = rp->z;
        }
        lx = __shfl(gx, 0, 64); ly = __shfl(gy, 0, 64); lz = __shfl(gz, 0, 64);
    }
    float* __restrict__ po = outp + b * (512*3);
    if (blk == 0 && t == 0) { po[0] = lx; po[1] = ly; po[2] = lz; }

    for (int s = 1; s < 512; ++s) {
        float bestv = NEG;
        int   bestc = 0x7FFFFFFF;
        // np order: dist = (dx*dx + dy*dy) + dz*dz, no fma; strict-> scan
        #pragma unroll
        for (int jo = 0; jo < 4; ++jo) {
            const int off = jo*2048 + t4;
            const float4 x4 = *(const float4*)(xs + off);
            const float4 y4 = *(const float4*)(ys + off);
            const float4 z4 = *(const float4*)(zs + off);
            float4 d4 = *(float4*)(ds + off);
            FBODY(x4.x, y4.x, z4.x, d4.x, jo*4 + 0)
            FBODY(x4.y, y4.y, z4.y, d4.y, jo*4 + 1)
            FBODY(x4.z, y4.z, z4.z, d4.z, jo*4 + 2)
            FBODY(x4.w, y4.w, z4.w, d4.w, jo*4 + 3)
            *(float4*)(ds + off) = d4;
        }
        if (t < 64) {   // tail: lp = 8192 + t, code 16
            const int off = 8192 + t;
            const float x0 = xs[off], y0 = ys[off], z0 = zs[off];
            float dd = ds[off];
            FBODY(x0, y0, z0, dd, 16)
            ds[off] = dd;
        }
        // decode code -> batch-global index
        const int lp = (bestc < 16) ? ((bestc >> 2)*2048 + t4 + (bestc & 3))
                                    : (8192 + t);
        int   besti = boff + lp;
        float bv = bestv;

        // wave argmax (min-index tie-break)
        #pragma unroll
        for (int m = 1; m < 64; m <<= 1) {
            const float ov = __shfl_xor(bv, m, 64);
            const int   oi = __shfl_xor(besti, m, 64);
            if (ov > bv || (ov == bv && oi < besti)) { bv = ov; besti = oi; }
        }
        const int par = s & 1;
        if ((t & 63) == 0) { redv[par][t >> 6] = bv; redi[par][t >> 6] = besti; }
        __syncthreads();
        // redundant block reduce over 8 wave partials
        float blv; int blg;
        {
            const int lane = t & 63;
            float v = (lane < 8) ? redv[par][lane] : NEG;
            int   i = (lane < 8) ? redi[par][lane] : 0x7FFFFFFF;
            #pragma unroll
            for (int m = 1; m < 8; m <<= 1) {
                const float ov = __shfl_xor(v, m, 64);
                const int   oi = __shfl_xor(i, m, 64);
                if (ov > v || (ov == v && oi < i)) { v = ov; i = oi; }
            }
            blv = __shfl(v, 0, 64); blg = __shfl(i, 0, 64);
        }
        // publish this block's candidate
        if (t == 0) {
            Rec* rp = Rb + s*NB + blk;
            const int li = blg - boff;
            rp->val = blv; rp->x = xs[li]; rp->y = ys[li]; rp->z = zs[li];
            __hip_atomic_store(&rp->idx, (unsigned)blg, __ATOMIC_RELEASE, __HIP_MEMORY_SCOPE_AGENT);
        }
        // gather the 4 candidates (redundant in every wave; lanes 0..3 poll)
        {
            const int lane = t & 63;
            float v = NEG; int i = 0x7FFFFFFF; float gx = 0.f, gy = 0.f, gz = 0.f;
            if (lane < NB) {
                Rec* rp = Rb + s*NB + lane;
                unsigned id;
                do { id = __hip_atomic_load(&rp->idx, __ATOMIC_ACQUIRE, __HIP_MEMORY_SCOPE_AGENT); }
                while (id == 0xAAAAAAAAu);
                v = rp->val; i = (int)id; gx = rp->x; gy = rp->y; gz = rp->z;
            }
            #pragma unroll
            for (int m = 1; m < 4; m <<= 1) {
                const float ov = __shfl_xor(v, m, 64);
                const int   oi = __shfl_xor(i, m, 64);
                const float ox = __shfl_xor(gx, m, 64);
                const float oy = __shfl_xor(gy, m, 64);
                const float oz = __shfl_xor(gz, m, 64);
                if (ov > v || (ov == v && oi < i)) { v = ov; i = oi; gx = ox; gy = oy; gz = oz; }
            }
            lx = __shfl(gx, 0, 64); ly = __shfl(gy, 0, 64); lz = __shfl(gz, 0, 64);
        }
        if (blk == 0 && t == 0) { po[s*3+0] = lx; po[s*3+1] = ly; po[s*3+2] = lz; }
    }
}

extern "C" void kernel_launch(void* const* d_in, const int* in_sizes, int n_in,
                              void* d_out, int out_size, void* d_ws, size_t ws_size,
                              hipStream_t stream)
{
    const float* feat    = (const float*)d_in[0];
    const float* partial = (const float*)d_in[1];
    const float* ps_w    = (const float*)d_in[2];
    const float* ps_b    = (const float*)d_in[3];
    const float* m1_w1   = (const float*)d_in[4];
    const float* m1_b1   = (const float*)d_in[5];
    const float* m1_w2   = (const float*)d_in[6];
    const float* m1_b2   = (const float*)d_in[7];
    const float* m1_ws   = (const float*)d_in[8];
    const float* m1_bs   = (const float*)d_in[9];
    const float* m2_w1   = (const float*)d_in[10];
    const float* m2_b1   = (const float*)d_in[11];
    const float* m2_w2   = (const float*)d_in[12];
    const float* m2_b2   = (const float*)d_in[13];
    const float* m2_ws   = (const float*)d_in[14];
    const float* m2_bs   = (const float*)d_in[15];
    const float* m3_w1   = (const float*)d_in[16];
    const float* m3_b1   = (const float*)d_in[17];
    const float* m3_w2   = (const float*)d_in[18];
    const float* m3_b2   = (const float*)d_in[19];
    const float* m3_ws   = (const float*)d_in[20];
    const float* m3_bs   = (const float*)d_in[21];
    const float* m4_w1   = (const float*)d_in[22];
    const float* m4_b1   = (const float*)d_in[23];
    const float* m4_w2   = (const float*)d_in[24];
    const float* m4_b2   = (const float*)d_in[25];

    float* ws = (float*)d_ws;
    float* XYZ = ws;              // 32*3*33024 = 3,170,304 floats (SoA per batch)
    float* A  = ws + 3170304;     // 1,048,576
    float* B  = ws + 4218880;     // 1,048,576
    float* C  = ws + 5267456;     // 1,048,576
    float* FB = ws + 6316032;     // 16,384
    Rec*  REC = (Rec*)(ws + 6332416);   // 32*512*4 recs * 32B = 2 MB

    float* out = (float*)d_out;   // [0,24576) pcd ; [24576,73728) p0

    // re-sentinel the record region EVERY call (no cross-call state)
    hipMemsetAsync(REC, 0xAA, (size_t)32*512*NB*sizeof(Rec), stream);

    k_ps  <<<128,  256, 0, stream>>>(feat, ps_w, ps_b, A);
    k_fb  <<<64,   256, 0, stream>>>(feat, m1_w1, m1_ws, m3_w1, m3_ws, FB);
    k_copy<<<4096, 256, 0, stream>>>(partial, XYZ);

    // m1 (fr folded into FB)
    k_conv<<<32*128, 256, 0, stream>>>(A, m1_w1, m1_b1, FB,       nullptr, B, 128, 128, 640, 1);
    k_conv<<<32*128, 256, 0, stream>>>(A, m1_ws, m1_bs, FB+4096,  nullptr, C, 128, 128, 640, 0);
    k_conv<<<32*128, 256, 0, stream>>>(B, m1_w2, m1_b2, nullptr,  C,       A, 128, 128, 128, 0);
    // m2
    k_conv<<<32*64,  256, 0, stream>>>(A, m2_w1, m2_b1, nullptr,  nullptr, B, 64,  128, 128, 1);
    k_conv<<<32*128, 256, 0, stream>>>(A, m2_ws, m2_bs, nullptr,  nullptr, C, 128, 128, 128, 0);
    k_conv<<<32*128, 256, 0, stream>>>(B, m2_w2, m2_b2, nullptr,  C,       A, 128, 64,  64,  0);
    // m3 (fr folded)
    k_conv<<<32*128, 256, 0, stream>>>(A, m3_w1, m3_b1, FB+8192,  nullptr, B, 128, 128, 640, 1);
    k_conv<<<32*128, 256, 0, stream>>>(A, m3_ws, m3_bs, FB+12288, nullptr, C, 128, 128, 640, 0);
    k_conv<<<32*128, 256, 0, stream>>>(B, m3_w2, m3_b2, nullptr,  C,       A, 128, 128, 128, 0);
    // m4
    k_conv<<<32*64,  256, 0, stream>>>(A, m4_w1, m4_b1, nullptr,  nullptr, B, 64,  128, 128, 1);
    k_conv<<<32*3,   256, 0, stream>>>(B, m4_w2, m4_b2, nullptr,  nullptr, C, 3,   64,  64,  0);

    k_pcd <<<32, 256, 0, stream>>>(C, out, XYZ);
    k_fps <<<32*NB, FPS_T, 0, stream>>>(XYZ, REC, out + 24576);
}

// Round 12
// 2144.044 us; speedup vs baseline: 4.8318x; 4.8318x over previous
//
#include <hip/hip_runtime.h>

#define NFULL 33024
#define FPS_T 512
#define BST   99072    // per-batch stride in XYZ SoA: 3*33024

typedef float v2f __attribute__((ext_vector_type(2)));
static __device__ __forceinline__ v2f mk2(float a, float b) { v2f r; r.x = a; r.y = b; return r; }

// ---- x1[b,o,k] = sum_i f[b,i] * ps_w[i,o,k] + ps_b[o] ; col = o*256+k ----
__global__ void k_ps(const float* __restrict__ feat,
                     const float* __restrict__ psw,
                     const float* __restrict__ psb,
                     float* __restrict__ out)
{
    __shared__ float fs[16384];   // all of f (32x512), 64 KB
    const int tid = threadIdx.x;
    for (int k = tid; k < 16384; k += 256) fs[k] = feat[k];
    __syncthreads();
    const int col = blockIdx.x * 256 + tid;    // 0..32767
    float acc[32];
    #pragma unroll
    for (int b = 0; b < 32; ++b) acc[b] = 0.f;
    for (int i = 0; i < 512; i += 4) {
        const float w0 = psw[(i+0)*32768 + col];
        const float w1 = psw[(i+1)*32768 + col];
        const float w2 = psw[(i+2)*32768 + col];
        const float w3 = psw[(i+3)*32768 + col];
        #pragma unroll
        for (int b = 0; b < 32; ++b) {
            const float4 f4 = *(const float4*)&fs[b*512 + i];
            acc[b] += f4.x*w0 + f4.y*w1 + f4.z*w2 + f4.w*w3;
        }
    }
    const float bias = psb[col >> 8];
    #pragma unroll
    for (int b = 0; b < 32; ++b) out[b*32768 + col] = acc[b] + bias;
}

// ---- fb[wsel][b,o] = sum_{i<512} f[b,i] * w[o*640 + 128 + i]  (fr-fold) ----
__global__ void k_fb(const float* __restrict__ feat,
                     const float* __restrict__ wa, const float* __restrict__ wb,
                     const float* __restrict__ wc, const float* __restrict__ wd,
                     float* __restrict__ fb)
{
    const int tid = blockIdx.x * 256 + threadIdx.x;  // 0..16383
    const int wsel = tid >> 12;
    const int r = tid & 4095;
    const int b = r >> 7, o = r & 127;
    const float* w = (wsel == 0 ? wa : wsel == 1 ? wb : wsel == 2 ? wc : wd) + o*640 + 128;
    const float* f = feat + b*512;
    float acc = 0.f;
    for (int i = 0; i < 512; i += 4) {
        const float4 wv = *(const float4*)(w + i);
        const float4 fv = *(const float4*)(f + i);
        acc += wv.x*fv.x + wv.y*fv.y + wv.z*fv.z + wv.w*fv.w;
    }
    fb[tid] = acc;
}

// ---- out[b,o,n] = relu?( sum_i w[o,i]*x[b,i,n] + bias[o] + fb[b,o] + add[b,o,n] )
__global__ void k_conv(const float* __restrict__ x,
                       const float* __restrict__ w,
                       const float* __restrict__ bias,
                       const float* __restrict__ fb,
                       const float* __restrict__ add,
                       float* __restrict__ out,
                       const int O, const int K, const int ldw, const int relu)
{
    const int bo = blockIdx.x;
    const int b = bo / O;
    const int o = bo - b * O;
    const int n = threadIdx.x;
    const float* __restrict__ wr = w + o * ldw;
    const float* __restrict__ xb = x + (b * K) * 256 + n;
    float acc = 0.f;
    for (int i = 0; i < K; i += 4) {
        const float4 wv = *(const float4*)(wr + i);
        acc += wv.x * xb[(i+0) << 8];
        acc += wv.y * xb[(i+1) << 8];
        acc += wv.z * xb[(i+2) << 8];
        acc += wv.w * xb[(i+3) << 8];
    }
    acc += bias[o];
    if (fb)   acc += fb[b * O + o];
    if (add)  acc += add[bo * 256 + n];
    if (relu) acc = fmaxf(acc, 0.f);
    out[bo * 256 + n] = acc;
}

// ---- pcd transpose -> d_out ; completion points -> XYZ SoA [0,256) ----
__global__ void k_pcd(const float* __restrict__ comp,
                      float* __restrict__ pcd_out,
                      float* __restrict__ XYZ)
{
    const int tid = blockIdx.x * 256 + threadIdx.x;  // 0..8191
    const int b = tid >> 8, n = tid & 255;
    const float cx = comp[(b*3+0)*256 + n];
    const float cy = comp[(b*3+1)*256 + n];
    const float cz = comp[(b*3+2)*256 + n];
    pcd_out[tid*3+0] = cx; pcd_out[tid*3+1] = cy; pcd_out[tid*3+2] = cz;
    float* Xb = XYZ + b*BST;
    Xb[n]           = cx;
    Xb[33024  + n]  = cy;
    Xb[66048  + n]  = cz;
}

// ---- partial (AoS) -> XYZ SoA [256,33024) per batch (bitwise) ----
__global__ void k_copy(const float* __restrict__ partial, float* __restrict__ XYZ)
{
    const int p = blockIdx.x*256 + threadIdx.x;   // 0..1048575 (32*32768)
    const int b = p >> 15, i = p & 32767;
    const float x = partial[p*3+0];
    const float y = partial[p*3+1];
    const float z = partial[p*3+2];
    float* Xb = XYZ + b*BST;
    Xb[256 + i]          = x;
    Xb[33024 + 256 + i]  = y;
    Xb[66048 + 256 + i]  = z;
}

// ================= farthest point sampling =================
// r9 structure (the only allocator-stable shape found in r1-r11): one
// 512-thread block per batch, ZERO persistent per-thread registers; the
// mutable d array in LDS (private per-thread float4 slots, no cross-thread
// hazard); x/y stream from L2-resident SoA. New in r12: (a) distance chain
// on float2 ext-vectors with fp-contract OFF -> backend emits packed
// v_pk_add/mul/min_f32 (two independent IEEE lanes, bitwise == the scalar
// __f*_rn chain); (b) z[0:6144) held in spare LDS (24KB), rest streamed.
// Multi-block variants are dead: r11 measured 19.6us/step for cross-block
// record exchange. Mapping p = jo*2048 + t4 + c; ascending code ==
// ascending index -> strict-> scan + min-index tie-break == np first-max.

#define FBODY(xx, yy, zz, dd, cc) { \
    const float dx = __fsub_rn((xx), lx); \
    const float dy = __fsub_rn((yy), ly); \
    const float dz = __fsub_rn((zz), lz); \
    const float dist = __fadd_rn(__fadd_rn(__fmul_rn(dx,dx), __fmul_rn(dy,dy)), \
                                 __fmul_rn(dz,dz)); \
    dd = fminf(dd, dist); \
    if (dd > bestv) { bestv = dd; bestc = (cc); } }

// 4 points via 2 packed lanes; ZP = z source array (zls for jo<3, Zb else)
#define FPS_GRP(jo, ZP) { \
    const int off = (jo)*2048 + t4; \
    const float4 x4 = *(const float4*)(Xb + off); \
    const float4 y4 = *(const float4*)(Yb + off); \
    const float4 z4 = *(const float4*)((ZP) + off); \
    float4 d4 = *(float4*)(dls + off); \
    v2f da, db; \
    { \
      _Pragma("clang fp contract(off)") \
      const v2f dxa = mk2(x4.x, x4.y) - lx2, dxb = mk2(x4.z, x4.w) - lx2; \
      const v2f dya = mk2(y4.x, y4.y) - ly2, dyb = mk2(y4.z, y4.w) - ly2; \
      const v2f dza = mk2(z4.x, z4.y) - lz2, dzb = mk2(z4.z, z4.w) - lz2; \
      const v2f sa = (dxa*dxa + dya*dya) + dza*dza; \
      const v2f sb = (dxb*dxb + dyb*dyb) + dzb*dzb; \
      da = __builtin_elementwise_min(mk2(d4.x, d4.y), sa); \
      db = __builtin_elementwise_min(mk2(d4.z, d4.w), sb); \
    } \
    d4.x = da.x; d4.y = da.y; d4.z = db.x; d4.w = db.y; \
    *(float4*)(dls + off) = d4; \
    if (da.x > bestv) { bestv = da.x; bestc = (jo)*4 + 0; } \
    if (da.y > bestv) { bestv = da.y; bestc = (jo)*4 + 1; } \
    if (db.x > bestv) { bestv = db.x; bestc = (jo)*4 + 2; } \
    if (db.y > bestv) { bestv = db.y; bestc = (jo)*4 + 3; } }

__launch_bounds__(FPS_T)
__global__ void k_fps(const float* __restrict__ XYZ, float* __restrict__ outp)
{
    __shared__ __align__(16) float dls[NFULL];   // 132,096 B: the d array
    __shared__ __align__(16) float zls[6144];    //  24,576 B: z for p<6144
    __shared__ float redv[2][8];
    __shared__ int   redi[2][8];

    const int b = blockIdx.x;
    const int t = threadIdx.x;
    const int t4 = t << 2;
    const float* __restrict__ Xb = XYZ + b*BST;
    const float* __restrict__ Yb = Xb + 33024;
    const float* __restrict__ Zb = Xb + 66048;
    const float NEG = -__builtin_inff();

    {   // init d = 1e10 over this thread's private slots; stage z slice
        const float4 v = make_float4(1.0e10f, 1.0e10f, 1.0e10f, 1.0e10f);
        #pragma unroll
        for (int jo = 0; jo < 16; ++jo) *(float4*)(dls + jo*2048 + t4) = v;
        if (t < 64) *(float4*)(dls + 32768 + t4) = v;
        for (int k = t; k < 6144; k += FPS_T) zls[k] = Zb[k];
    }
    __syncthreads();

    int last = 0;
    float* __restrict__ po = outp + b * (512*3);
    for (int s = 0; s < 512; ++s) {
        const float lx = Xb[last];    // broadcast L2 hits
        const float ly = Yb[last];
        const float lz = Zb[last];
        if (t == 0) { po[s*3+0] = lx; po[s*3+1] = ly; po[s*3+2] = lz; }
        if (s == 511) break;
        const v2f lx2 = mk2(lx, lx), ly2 = mk2(ly, ly), lz2 = mk2(lz, lz);

        float bestv = NEG;
        int   bestc = 0x7FFFFFFF;
        // np order: dist = (dx*dx + dy*dy) + dz*dz, no fma; strict-> scan
        FPS_GRP(0, zls) FPS_GRP(1, zls) FPS_GRP(2, zls)
        FPS_GRP(3, Zb)  FPS_GRP(4, Zb)  FPS_GRP(5, Zb)  FPS_GRP(6, Zb)
        FPS_GRP(7, Zb)  FPS_GRP(8, Zb)  FPS_GRP(9, Zb)  FPS_GRP(10, Zb)
        FPS_GRP(11, Zb) FPS_GRP(12, Zb) FPS_GRP(13, Zb) FPS_GRP(14, Zb)
        FPS_GRP(15, Zb)
        if (t < 64) {   // tail points 32768..33023, codes 64..67
            const int off = 32768 + t4;
            const float4 x4 = *(const float4*)(Xb + off);
            const float4 y4 = *(const float4*)(Yb + off);
            const float4 z4 = *(const float4*)(Zb + off);
            float4 d4 = *(float4*)(dls + off);
            FBODY(x4.x, y4.x, z4.x, d4.x, 64)
            FBODY(x4.y, y4.y, z4.y, d4.y, 65)
            FBODY(x4.z, y4.z, z4.z, d4.z, 66)
            FBODY(x4.w, y4.w, z4.w, d4.w, 67)
            *(float4*)(dls + off) = d4;
        }
        // decode code -> global index: ((code>>2)<<11) + t4 + (code&3)
        int besti = ((bestc >> 2) << 11) + t4 + (bestc & 3);

        // wave (64-lane) argmax reduce, min-index tie-break
        #pragma unroll
        for (int m = 1; m < 64; m <<= 1) {
            const float ov = __shfl_xor(bestv, m, 64);
            const int   oi = __shfl_xor(besti, m, 64);
            if (ov > bestv || (ov == bestv && oi < besti)) { bestv = ov; besti = oi; }
        }
        const int bank = s & 1;
        if ((t & 63) == 0) { redv[bank][t >> 6] = bestv; redi[bank][t >> 6] = besti; }
        __syncthreads();
        // every wave redundantly reduces the 8 partials (no 2nd barrier;
        // banks are step-parity double-buffered)
        {
            const int lane = t & 63;
            float v = (lane < 8) ? redv[bank][lane] : NEG;
            int   i = (lane < 8) ? redi[bank][lane] : 0x7FFFFFFF;
            #pragma unroll
            for (int m = 1; m < 8; m <<= 1) {
                const float ov = __shfl_xor(v, m, 64);
                const int   oi = __shfl_xor(i, m, 64);
                if (ov > v || (ov == v && oi < i)) { v = ov; i = oi; }
            }
            last = __shfl(i, 0, 64);
        }
    }
}

extern "C" void kernel_launch(void* const* d_in, const int* in_sizes, int n_in,
                              void* d_out, int out_size, void* d_ws, size_t ws_size,
                              hipStream_t stream)
{
    const float* feat    = (const float*)d_in[0];
    const float* partial = (const float*)d_in[1];
    const float* ps_w    = (const float*)d_in[2];
    const float* ps_b    = (const float*)d_in[3];
    const float* m1_w1   = (const float*)d_in[4];
    const float* m1_b1   = (const float*)d_in[5];
    const float* m1_w2   = (const float*)d_in[6];
    const float* m1_b2   = (const float*)d_in[7];
    const float* m1_ws   = (const float*)d_in[8];
    const float* m1_bs   = (const float*)d_in[9];
    const float* m2_w1   = (const float*)d_in[10];
    const float* m2_b1   = (const float*)d_in[11];
    const float* m2_w2   = (const float*)d_in[12];
    const float* m2_b2   = (const float*)d_in[13];
    const float* m2_ws   = (const float*)d_in[14];
    const float* m2_bs   = (const float*)d_in[15];
    const float* m3_w1   = (const float*)d_in[16];
    const float* m3_b1   = (const float*)d_in[17];
    const float* m3_w2   = (const float*)d_in[18];
    const float* m3_b2   = (const float*)d_in[19];
    const float* m3_ws   = (const float*)d_in[20];
    const float* m3_bs   = (const float*)d_in[21];
    const float* m4_w1   = (const float*)d_in[22];
    const float* m4_b1   = (const float*)d_in[23];
    const float* m4_w2   = (const float*)d_in[24];
    const float* m4_b2   = (const float*)d_in[25];

    float* ws = (float*)d_ws;
    float* XYZ = ws;              // 32*3*33024 = 3,170,304 floats (SoA per batch)
    float* A  = ws + 3170304;     // 1,048,576
    float* B  = ws + 4218880;     // 1,048,576
    float* C  = ws + 5267456;     // 1,048,576
    float* FB = ws + 6316032;     // 4*4096 (m1_w1, m1_ws, m3_w1, m3_ws folds)

    float* out = (float*)d_out;   // [0,24576) pcd ; [24576,73728) p0

    k_ps  <<<128,  256, 0, stream>>>(feat, ps_w, ps_b, A);
    k_fb  <<<64,   256, 0, stream>>>(feat, m1_w1, m1_ws, m3_w1, m3_ws, FB);
    k_copy<<<4096, 256, 0, stream>>>(partial, XYZ);

    // m1 (fr folded into FB)
    k_conv<<<32*128, 256, 0, stream>>>(A, m1_w1, m1_b1, FB,       nullptr, B, 128, 128, 640, 1);
    k_conv<<<32*128, 256, 0, stream>>>(A, m1_ws, m1_bs, FB+4096,  nullptr, C, 128, 128, 640, 0);
    k_conv<<<32*128, 256, 0, stream>>>(B, m1_w2, m1_b2, nullptr,  C,       A, 128, 128, 128, 0);
    // m2
    k_conv<<<32*64,  256, 0, stream>>>(A, m2_w1, m2_b1, nullptr,  nullptr, B, 64,  128, 128, 1);
    k_conv<<<32*128, 256, 0, stream>>>(A, m2_ws, m2_bs, nullptr,  nullptr, C, 128, 128, 128, 0);
    k_conv<<<32*128, 256, 0, stream>>>(B, m2_w2, m2_b2, nullptr,  C,       A, 128, 64,  64,  0);
    // m3 (fr folded)
    k_conv<<<32*128, 256, 0, stream>>>(A, m3_w1, m3_b1, FB+8192,  nullptr, B, 128, 128, 640, 1);
    k_conv<<<32*128, 256, 0, stream>>>(A, m3_ws, m3_bs, FB+12288, nullptr, C, 128, 128, 640, 0);
    k_conv<<<32*128, 256, 0, stream>>>(B, m3_w2, m3_b2, nullptr,  C,       A, 128, 128, 128, 0);
    // m4
    k_conv<<<32*64,  256, 0, stream>>>(A, m4_w1, m4_b1, nullptr,  nullptr, B, 64,  128, 128, 1);
    k_conv<<<32*3,   256, 0, stream>>>(B, m4_w2, m4_b2, nullptr,  nullptr, C, 3,   64,  64,  0);

    k_pcd <<<32, 256, 0, stream>>>(C, out, XYZ);
    k_fps <<<32, FPS_T, 0, stream>>>(XYZ, out + 24576);
}